// Round 1
// baseline (6524.895 us; speedup 1.0000x reference)
//
#include <hip/hip_runtime.h>
#include <math.h>

#define NV 20000
#define ME 5000
#define EI_N 160000
#define CD 1024
#define HD 512
#define NCO 10

// ---------------- reduction helpers ----------------
__device__ __forceinline__ float blockReduceSum(float v) {
    __shared__ float sh[16];
    int lane = threadIdx.x & 63, wid = threadIdx.x >> 6;
    for (int o = 32; o; o >>= 1) v += __shfl_xor(v, o);
    if (lane == 0) sh[wid] = v;
    __syncthreads();
    float r = (threadIdx.x < (blockDim.x >> 6)) ? sh[threadIdx.x] : 0.f;
    if (wid == 0) {
        for (int o = 32; o; o >>= 1) r += __shfl_xor(r, o);
        if (lane == 0) sh[0] = r;
    }
    __syncthreads();
    r = sh[0];
    __syncthreads();
    return r;
}

__device__ __forceinline__ float blockReduceMax(float v) {
    __shared__ float sh[16];
    int lane = threadIdx.x & 63, wid = threadIdx.x >> 6;
    for (int o = 32; o; o >>= 1) v = fmaxf(v, __shfl_xor(v, o));
    if (lane == 0) sh[wid] = v;
    __syncthreads();
    float r = (threadIdx.x < (blockDim.x >> 6)) ? sh[threadIdx.x] : -INFINITY;
    if (wid == 0) {
        for (int o = 32; o; o >>= 1) r = fmaxf(r, __shfl_xor(r, o));
        if (lane == 0) sh[0] = r;
    }
    __syncthreads();
    r = sh[0];
    __syncthreads();
    return r;
}

// ---------------- CSR build ----------------
__global__ void k_count(const int* __restrict__ idx, int* __restrict__ cnt, int n) {
    int i = blockIdx.x * blockDim.x + threadIdx.x;
    if (i < n) atomicAdd(&cnt[idx[i]], 1);
}

// single-block exclusive scan over cnt -> off, zero pos, off[n]=total
__global__ void k_scan(const int* __restrict__ cnt, int* __restrict__ off,
                       int* __restrict__ pos, int n) {
    __shared__ int sdata[1024];
    __shared__ int carry;
    int tid = threadIdx.x;
    if (tid == 0) carry = 0;
    __syncthreads();
    for (int base = 0; base < n; base += 1024) {
        int i = base + tid;
        int v = (i < n) ? cnt[i] : 0;
        sdata[tid] = v;
        __syncthreads();
        for (int o = 1; o < 1024; o <<= 1) {
            int t = (tid >= o) ? sdata[tid - o] : 0;
            __syncthreads();
            sdata[tid] += t;
            __syncthreads();
        }
        int incl = sdata[tid];
        if (i < n) { off[i] = carry + incl - v; pos[i] = 0; }
        __syncthreads();
        if (tid == 1023) carry += incl;
        __syncthreads();
    }
    if (tid == 0) off[n] = carry;
}

// mode 0: list[slot] = other[k]   (e-CSR stores vertex id)
// mode 1: list[slot] = k          (v-CSR stores incidence index)
__global__ void k_scatter(const int* __restrict__ idx, const int* __restrict__ other,
                          int* __restrict__ pos, const int* __restrict__ off,
                          int* __restrict__ list, int n, int mode) {
    int k = blockIdx.x * blockDim.x + threadIdx.x;
    if (k >= n) return;
    int s = idx[k];
    int p = atomicAdd(&pos[s], 1);
    list[off[s] + p] = mode ? k : other[k];
}

// ---------------- GEMM: C = A @ B^T + bias  (A[M,K], B[N,K] row-major) ----------------
#define GT 64
#define GK 16
__global__ __launch_bounds__(256) void k_gemm(const float* __restrict__ A,
                                              const float* __restrict__ B,
                                              const float* __restrict__ bias,
                                              float* __restrict__ C,
                                              int Mr, int Nc, int K) {
    __shared__ float As[GK][GT + 4];
    __shared__ float Bs[GK][GT + 4];
    const int tid = threadIdx.x;
    const int tx = tid & 15, ty = tid >> 4;
    const int rowBase = blockIdx.x * GT, colBase = blockIdx.y * GT;
    const int lr = tid >> 2, lk = (tid & 3) << 2;
    const int ar = rowBase + lr;
    const int br = colBase + lr;   // Nc is a multiple of 64 -> always valid
    float acc[4][4] = {};
    for (int kk = 0; kk < K; kk += GK) {
        float4 av = make_float4(0.f, 0.f, 0.f, 0.f);
        if (ar < Mr) av = *(const float4*)(A + (size_t)ar * K + kk + lk);
        float4 bv = *(const float4*)(B + (size_t)br * K + kk + lk);
        As[lk][lr] = av.x; As[lk + 1][lr] = av.y; As[lk + 2][lr] = av.z; As[lk + 3][lr] = av.w;
        Bs[lk][lr] = bv.x; Bs[lk + 1][lr] = bv.y; Bs[lk + 2][lr] = bv.z; Bs[lk + 3][lr] = bv.w;
        __syncthreads();
#pragma unroll
        for (int k = 0; k < GK; ++k) {
            float4 a = *(const float4*)&As[k][ty << 2];
            float4 b = *(const float4*)&Bs[k][tx << 2];
            acc[0][0] += a.x * b.x; acc[0][1] += a.x * b.y; acc[0][2] += a.x * b.z; acc[0][3] += a.x * b.w;
            acc[1][0] += a.y * b.x; acc[1][1] += a.y * b.y; acc[1][2] += a.y * b.z; acc[1][3] += a.y * b.w;
            acc[2][0] += a.z * b.x; acc[2][1] += a.z * b.y; acc[2][2] += a.z * b.z; acc[2][3] += a.z * b.w;
            acc[3][0] += a.w * b.x; acc[3][1] += a.w * b.y; acc[3][2] += a.w * b.z; acc[3][3] += a.w * b.w;
        }
        __syncthreads();
    }
#pragma unroll
    for (int i = 0; i < 4; ++i) {
        int r = rowBase + (ty << 2) + i;
        if (r < Mr) {
            int c0 = colBase + (tx << 2);
            float4 o;
            o.x = acc[i][0] + bias[c0];
            o.y = acc[i][1] + bias[c0 + 1];
            o.z = acc[i][2] + bias[c0 + 2];
            o.w = acc[i][3] + bias[c0 + 3];
            *(float4*)(C + (size_t)r * Nc + c0) = o;
        }
    }
}

// dual GEMM for gated attention: Aout = tanh(X@Wa^T+ba) * sigmoid(X@Wb^T+bb), Nc=256
__global__ __launch_bounds__(256) void k_gemm_dual(const float* __restrict__ X,
                                                   const float* __restrict__ Wa,
                                                   const float* __restrict__ ba,
                                                   const float* __restrict__ Wb,
                                                   const float* __restrict__ bb,
                                                   float* __restrict__ Aout,
                                                   int Mr, int K) {
    __shared__ float As[GK][GT + 4];
    __shared__ float B1[GK][GT + 4];
    __shared__ float B2[GK][GT + 4];
    const int tid = threadIdx.x;
    const int tx = tid & 15, ty = tid >> 4;
    const int rowBase = blockIdx.x * GT, colBase = blockIdx.y * GT;
    const int lr = tid >> 2, lk = (tid & 3) << 2;
    const int ar = rowBase + lr;
    const int br = colBase + lr;
    float acc1[4][4] = {}, acc2[4][4] = {};
    for (int kk = 0; kk < K; kk += GK) {
        float4 av = make_float4(0.f, 0.f, 0.f, 0.f);
        if (ar < Mr) av = *(const float4*)(X + (size_t)ar * K + kk + lk);
        float4 b1 = *(const float4*)(Wa + (size_t)br * K + kk + lk);
        float4 b2 = *(const float4*)(Wb + (size_t)br * K + kk + lk);
        As[lk][lr] = av.x; As[lk + 1][lr] = av.y; As[lk + 2][lr] = av.z; As[lk + 3][lr] = av.w;
        B1[lk][lr] = b1.x; B1[lk + 1][lr] = b1.y; B1[lk + 2][lr] = b1.z; B1[lk + 3][lr] = b1.w;
        B2[lk][lr] = b2.x; B2[lk + 1][lr] = b2.y; B2[lk + 2][lr] = b2.z; B2[lk + 3][lr] = b2.w;
        __syncthreads();
#pragma unroll
        for (int k = 0; k < GK; ++k) {
            float4 a = *(const float4*)&As[k][ty << 2];
            float4 p = *(const float4*)&B1[k][tx << 2];
            float4 q = *(const float4*)&B2[k][tx << 2];
            acc1[0][0] += a.x * p.x; acc1[0][1] += a.x * p.y; acc1[0][2] += a.x * p.z; acc1[0][3] += a.x * p.w;
            acc1[1][0] += a.y * p.x; acc1[1][1] += a.y * p.y; acc1[1][2] += a.y * p.z; acc1[1][3] += a.y * p.w;
            acc1[2][0] += a.z * p.x; acc1[2][1] += a.z * p.y; acc1[2][2] += a.z * p.z; acc1[2][3] += a.z * p.w;
            acc1[3][0] += a.w * p.x; acc1[3][1] += a.w * p.y; acc1[3][2] += a.w * p.z; acc1[3][3] += a.w * p.w;
            acc2[0][0] += a.x * q.x; acc2[0][1] += a.x * q.y; acc2[0][2] += a.x * q.z; acc2[0][3] += a.x * q.w;
            acc2[1][0] += a.y * q.x; acc2[1][1] += a.y * q.y; acc2[1][2] += a.y * q.z; acc2[1][3] += a.y * q.w;
            acc2[2][0] += a.z * q.x; acc2[2][1] += a.z * q.y; acc2[2][2] += a.z * q.z; acc2[2][3] += a.z * q.w;
            acc2[3][0] += a.w * q.x; acc2[3][1] += a.w * q.y; acc2[3][2] += a.w * q.z; acc2[3][3] += a.w * q.w;
        }
        __syncthreads();
    }
#pragma unroll
    for (int i = 0; i < 4; ++i) {
        int r = rowBase + (ty << 2) + i;
        if (r < Mr) {
            int c0 = colBase + (tx << 2);
            float4 o;
#pragma unroll
            for (int j = 0; j < 4; ++j) {
                float t = tanhf(acc1[i][j] + ba[c0 + j]);
                float s = 1.f / (1.f + expf(-(acc2[i][j] + bb[c0 + j])));
                ((float*)&o)[j] = t * s;
            }
            *(float4*)(Aout + (size_t)r * 256 + c0) = o;
        }
    }
}

// ---------------- segment ops ----------------
// Y[e] = mean over incident vertices of Xin[v]
__global__ void k_v2e(const float* __restrict__ Xin, float* __restrict__ Y,
                      const int* __restrict__ e_off, const int* __restrict__ e_list, int D) {
    int e = blockIdx.x;
    int c = blockIdx.y * blockDim.x + threadIdx.x;
    int beg = e_off[e], end = e_off[e + 1];
    float acc = 0.f;
    for (int p = beg; p < end; ++p) {
        int v = e_list[p];
        acc += Xin[(size_t)v * D + c];
    }
    float deg = (float)(end - beg);
    Y[(size_t)e * D + c] = acc / fmaxf(deg, 1.f);
}

// alpha[e] = Y[e] . we
__global__ void k_alpha(const float* __restrict__ Y, const float* __restrict__ we,
                        float* __restrict__ alpha, int Mrows, int D) {
    int w = (blockIdx.x * blockDim.x + threadIdx.x) >> 6;
    int lane = threadIdx.x & 63;
    if (w >= Mrows) return;
    float acc = 0.f;
    for (int c = lane; c < D; c += 64) acc += Y[(size_t)w * D + c] * we[c];
    for (int o = 32; o; o >>= 1) acc += __shfl_xor(acc, o);
    if (!lane) alpha[w] = acc;
}

// per-vertex softmax over incident leaky_relu(alpha[e]) scores; one wave per vertex
__global__ void k_segsoftmax(const float* __restrict__ alpha, const int* __restrict__ e_idx,
                             const int* __restrict__ v_off, const int* __restrict__ v_list,
                             float* __restrict__ w, int n) {
    int v = (blockIdx.x * blockDim.x + threadIdx.x) >> 6;
    int lane = threadIdx.x & 63;
    if (v >= n) return;
    int beg = v_off[v], end = v_off[v + 1];
    if (beg == end) return;
    float m = -INFINITY;
    for (int p = beg + lane; p < end; p += 64) {
        float a = alpha[e_idx[v_list[p]]];
        float s = a > 0.f ? a : 0.2f * a;
        m = fmaxf(m, s);
    }
    for (int o = 32; o; o >>= 1) m = fmaxf(m, __shfl_xor(m, o));
    float sum = 0.f;
    for (int p = beg + lane; p < end; p += 64) {
        float a = alpha[e_idx[v_list[p]]];
        float s = a > 0.f ? a : 0.2f * a;
        sum += expf(s - m);
    }
    for (int o = 32; o; o >>= 1) sum += __shfl_xor(sum, o);
    float inv = 1.f / (sum + 1e-12f);
    for (int p = beg + lane; p < end; p += 64) {
        int k = v_list[p];
        float a = alpha[e_idx[k]];
        float s = a > 0.f ? a : 0.2f * a;
        w[k] = expf(s - m) * inv;
    }
}

// Xo[v] = sum over incidences w[k]*Y[e_idx[k]]; optional elu
__global__ void k_e2v(const float* __restrict__ Y, const float* __restrict__ w,
                      const int* __restrict__ e_idx, const int* __restrict__ v_off,
                      const int* __restrict__ v_list, float* __restrict__ Xo, int D, int act) {
    int v = blockIdx.x;
    int c = blockIdx.y * blockDim.x + threadIdx.x;
    int beg = v_off[v], end = v_off[v + 1];
    float acc = 0.f;
    for (int p = beg; p < end; ++p) {
        int k = v_list[p];
        acc += w[k] * Y[(size_t)e_idx[k] * D + c];
    }
    if (act && acc < 0.f) acc = expm1f(acc);
    Xo[(size_t)v * D + c] = acc;
}

// ---------------- attention tail ----------------
__global__ void k_logits(const float* __restrict__ Amat, const float* __restrict__ Wc,
                         const float* __restrict__ bc, float* __restrict__ logits, int n) {
    int i = (blockIdx.x * blockDim.x + threadIdx.x) >> 6;
    int lane = threadIdx.x & 63;
    if (i >= n) return;
    float4 a = *(const float4*)(Amat + (size_t)i * 256 + lane * 4);
    float4 wv = *(const float4*)(Wc + lane * 4);
    float acc = a.x * wv.x + a.y * wv.y + a.z * wv.z + a.w * wv.w;
    for (int o = 32; o; o >>= 1) acc += __shfl_xor(acc, o);
    if (!lane) logits[i] = acc + bc[0];
}

__global__ void k_maxpart(const float* __restrict__ x, int n, float* __restrict__ part) {
    float m = -INFINITY;
    for (int i = blockIdx.x * blockDim.x + threadIdx.x; i < n; i += gridDim.x * blockDim.x)
        m = fmaxf(m, x[i]);
    m = blockReduceMax(m);
    if (!threadIdx.x) part[blockIdx.x] = m;
}
__global__ void k_maxfin(const float* __restrict__ part, int np, float* __restrict__ red) {
    float m = (threadIdx.x < np) ? part[threadIdx.x] : -INFINITY;
    m = blockReduceMax(m);
    if (!threadIdx.x) red[0] = m;
}
__global__ void k_exppart(const float* __restrict__ x, int n, const float* __restrict__ red,
                          float* __restrict__ evec, float* __restrict__ part) {
    float m = red[0];
    float s = 0.f;
    for (int i = blockIdx.x * blockDim.x + threadIdx.x; i < n; i += gridDim.x * blockDim.x) {
        float e = expf(x[i] - m);
        evec[i] = e;
        s += e;
    }
    s = blockReduceSum(s);
    if (!threadIdx.x) part[blockIdx.x] = s;
}
__global__ void k_sumfin(const float* __restrict__ part, int np, float* __restrict__ red) {
    float s = (threadIdx.x < np) ? part[threadIdx.x] : 0.f;
    s = blockReduceSum(s);
    if (!threadIdx.x) red[1] = s;
}

// gpart[chunk][c] = sum over chunk rows evec[i]*H[i,c]
__global__ void k_wcolsum(const float* __restrict__ H, const float* __restrict__ evec,
                          float* __restrict__ gpart, int n, int D, int rows_per) {
    int c = blockIdx.x * blockDim.x + threadIdx.x;
    int r0 = blockIdx.y * rows_per;
    int r1 = min(r0 + rows_per, n);
    float acc = 0.f;
    for (int i = r0; i < r1; ++i) acc += evec[i] * H[(size_t)i * D + c];
    gpart[(size_t)blockIdx.y * D + c] = acc;
}
__global__ void k_colfin(const float* __restrict__ gpart, int nch, int D,
                         const float* __restrict__ red, float* __restrict__ g) {
    int c = blockIdx.x * blockDim.x + threadIdx.x;
    float acc = 0.f;
    for (int ch = 0; ch < nch; ++ch) acc += gpart[(size_t)ch * D + c];
    g[c] = acc / red[1];
}

// out[j] = g . Wout[j] + b[j]
__global__ void k_matvec(const float* __restrict__ g, const float* __restrict__ W,
                         const float* __restrict__ b, float* __restrict__ out, int D) {
    int j = (blockIdx.x * blockDim.x + threadIdx.x) >> 6;
    int lane = threadIdx.x & 63;
    if (j >= D) return;
    float acc = 0.f;
    for (int k = lane * 4; k < D; k += 256) {
        float4 w4 = *(const float4*)(W + (size_t)j * D + k);
        float4 g4 = *(const float4*)(g + k);
        acc += w4.x * g4.x + w4.y * g4.y + w4.z * g4.z + w4.w * g4.w;
    }
    for (int o = 32; o; o >>= 1) acc += __shfl_xor(acc, o);
    if (!lane) out[j] = acc + b[j];
}

// single-block layernorm of a D-vector
__global__ void k_ln(const float* __restrict__ x, const float* __restrict__ gam,
                     const float* __restrict__ bet, float* __restrict__ out, int D) {
    float s = 0.f, s2 = 0.f;
    for (int i = threadIdx.x; i < D; i += blockDim.x) {
        float v = x[i];
        s += v;
        s2 += v * v;
    }
    s = blockReduceSum(s);
    s2 = blockReduceSum(s2);
    float mu = s / D;
    float var = s2 / D - mu * mu;
    float inv = rsqrtf(var + 1e-5f);
    for (int i = threadIdx.x; i < D; i += blockDim.x)
        out[i] = (x[i] - mu) * inv * gam[i] + bet[i];
}

// final: ln(xcat[6144]) @ Wf^T + bf -> out[10]
__global__ void k_head(const float* __restrict__ xcat, const float* __restrict__ g2,
                       const float* __restrict__ b2, const float* __restrict__ Wf,
                       const float* __restrict__ bf, float* __restrict__ out) {
    __shared__ float xn[6 * CD];
    float s = 0.f, s2 = 0.f;
    for (int i = threadIdx.x; i < 6 * CD; i += blockDim.x) {
        float v = xcat[i];
        s += v;
        s2 += v * v;
    }
    s = blockReduceSum(s);
    s2 = blockReduceSum(s2);
    float mu = s / (6 * CD);
    float var = s2 / (6 * CD) - mu * mu;
    float inv = rsqrtf(var + 1e-5f);
    for (int i = threadIdx.x; i < 6 * CD; i += blockDim.x)
        xn[i] = (xcat[i] - mu) * inv * g2[i] + b2[i];
    __syncthreads();
    for (int o = 0; o < NCO; ++o) {
        float a = 0.f;
        for (int i = threadIdx.x; i < 6 * CD; i += blockDim.x)
            a += xn[i] * Wf[(size_t)o * 6 * CD + i];
        a = blockReduceSum(a);
        if (!threadIdx.x) out[o] = a + bf[o];
    }
}

// ---------------- host launcher ----------------
extern "C" void kernel_launch(void* const* d_in, const int* in_sizes, int n_in,
                              void* d_out, int out_size, void* d_ws, size_t ws_size,
                              hipStream_t stream) {
    (void)in_sizes; (void)n_in; (void)out_size; (void)ws_size;

    const float* X[3];
    const int* VI[3];
    const int* EIx[3];
    for (int b = 0; b < 3; ++b) {
        X[b] = (const float*)d_in[3 * b + 0];
        VI[b] = (const int*)d_in[3 * b + 1];
        EIx[b] = (const int*)d_in[3 * b + 2];
    }
    const float* Wt0 = (const float*)d_in[9];
    const float* bt0 = (const float*)d_in[10];
    const float* we0 = (const float*)d_in[11];
    const float* Wt1 = (const float*)d_in[12];
    const float* bt1 = (const float*)d_in[13];
    const float* we1 = (const float*)d_in[14];
    const float* Wa = (const float*)d_in[15];
    const float* ba = (const float*)d_in[16];
    const float* Wb = (const float*)d_in[17];
    const float* bb = (const float*)d_in[18];
    const float* Wc = (const float*)d_in[19];
    const float* bc = (const float*)d_in[20];
    const float* Wout = (const float*)d_in[21];
    const float* bout = (const float*)d_in[22];
    const float* g_bn = (const float*)d_in[23];
    const float* b_bn = (const float*)d_in[24];
    const float* g_bn2 = (const float*)d_in[25];
    const float* b_bn2 = (const float*)d_in[26];
    const float* Wf = (const float*)d_in[27];
    const float* bf = (const float*)d_in[28];

    // workspace layout (floats, 256B-aligned chunks)
    float* wsf = (float*)d_ws;
    size_t off = 0;
    auto falloc = [&](size_t nelem) {
        float* p = wsf + off;
        off += (nelem + 63) & ~(size_t)63;
        return p;
    };
    float* bufA = falloc((size_t)NV * CD);   // layer-1 theta out, then final h
    float* bufH = falloc((size_t)NV * HD);   // layer-0 out; reused as attn A-matrix
    float* bufY = falloc((size_t)ME * CD);   // Y0/Y1/y
    float* alpha = falloc(ME);
    float* wgt = falloc(EI_N);
    float* logits = falloc(NV);
    float* evec = falloc(NV);
    float* red = falloc(64);
    float* part = falloc(512);
    float* gpart = falloc((size_t)64 * CD);
    float* gvec = falloc(CD);
    float* gout = falloc(CD);
    float* xcat = falloc(8 * 1024);

    int* wsi = (int*)(wsf + off);
    size_t ioff = 0;
    auto ialloc = [&](size_t nelem) {
        int* p = wsi + ioff;
        ioff += (nelem + 63) & ~(size_t)63;
        return p;
    };
    int* e_cnt = ialloc(ME);
    int* e_off = ialloc(ME + 1);
    int* e_pos = ialloc(ME);
    int* e_list = ialloc(EI_N);
    int* v_cnt = ialloc(NV);
    int* v_off = ialloc(NV + 1);
    int* v_pos = ialloc(NV);
    int* v_list = ialloc(EI_N);

    auto attn = [&](const float* Xm, int n, float* dst) {
        float* Am = bufH;  // [n,256]
        k_gemm_dual<<<dim3((n + GT - 1) / GT, 256 / GT), 256, 0, stream>>>(Xm, Wa, ba, Wb, bb, Am, n, CD);
        k_logits<<<(n + 3) / 4, 256, 0, stream>>>(Am, Wc, bc, logits, n);
        k_maxpart<<<256, 256, 0, stream>>>(logits, n, part);
        k_maxfin<<<1, 256, 0, stream>>>(part, 256, red);
        k_exppart<<<256, 256, 0, stream>>>(logits, n, red, evec, part);
        k_sumfin<<<1, 256, 0, stream>>>(part, 256, red);
        int nch = (n >= NV) ? 50 : 10;
        int rows_per = (n + nch - 1) / nch;
        k_wcolsum<<<dim3(CD / 256, nch), 256, 0, stream>>>(Xm, evec, gpart, n, CD, rows_per);
        k_colfin<<<CD / 256, 256, 0, stream>>>(gpart, nch, CD, red, gvec);
        k_matvec<<<CD / 4, 256, 0, stream>>>(gvec, Wout, bout, gout, CD);
        k_ln<<<1, 256, 0, stream>>>(gout, g_bn, b_bn, dst, CD);
    };

    for (int b = 0; b < 3; ++b) {
        // ---- CSR build ----
        hipMemsetAsync(e_cnt, 0, ME * sizeof(int), stream);
        hipMemsetAsync(v_cnt, 0, NV * sizeof(int), stream);
        k_count<<<(EI_N + 255) / 256, 256, 0, stream>>>(EIx[b], e_cnt, EI_N);
        k_count<<<(EI_N + 255) / 256, 256, 0, stream>>>(VI[b], v_cnt, EI_N);
        k_scan<<<1, 1024, 0, stream>>>(e_cnt, e_off, e_pos, ME);
        k_scan<<<1, 1024, 0, stream>>>(v_cnt, v_off, v_pos, NV);
        k_scatter<<<(EI_N + 255) / 256, 256, 0, stream>>>(EIx[b], VI[b], e_pos, e_off, e_list, EI_N, 0);
        k_scatter<<<(EI_N + 255) / 256, 256, 0, stream>>>(VI[b], EIx[b], v_pos, v_off, v_list, EI_N, 1);

        // ---- UniGAT layer 0 (out=HD, elu) ----
        k_gemm<<<dim3((NV + GT - 1) / GT, HD / GT), 256, 0, stream>>>(X[b], Wt0, bt0, bufH, NV, HD, CD);
        k_v2e<<<dim3(ME, HD / 256), 256, 0, stream>>>(bufH, bufY, e_off, e_list, HD);
        k_alpha<<<(ME + 3) / 4, 256, 0, stream>>>(bufY, we0, alpha, ME, HD);
        k_segsoftmax<<<(NV + 3) / 4, 256, 0, stream>>>(alpha, EIx[b], v_off, v_list, wgt, NV);
        k_e2v<<<dim3(NV, HD / 256), 256, 0, stream>>>(bufY, wgt, EIx[b], v_off, v_list, bufH, HD, 1);

        // ---- UniGAT layer 1 (out=CD, no act) ----
        k_gemm<<<dim3((NV + GT - 1) / GT, CD / GT), 256, 0, stream>>>(bufH, Wt1, bt1, bufA, NV, CD, HD);
        k_v2e<<<dim3(ME, CD / 256), 256, 0, stream>>>(bufA, bufY, e_off, e_list, CD);
        k_alpha<<<(ME + 3) / 4, 256, 0, stream>>>(bufY, we1, alpha, ME, CD);
        k_segsoftmax<<<(NV + 3) / 4, 256, 0, stream>>>(alpha, EIx[b], v_off, v_list, wgt, NV);
        k_e2v<<<dim3(NV, CD / 256), 256, 0, stream>>>(bufY, wgt, EIx[b], v_off, v_list, bufA, CD, 0);

        // ---- y = v2e_mean(h) ----
        k_v2e<<<dim3(ME, CD / 256), 256, 0, stream>>>(bufA, bufY, e_off, e_list, CD);

        // ---- gated attention heads ----
        attn(bufA, NV, xcat + (size_t)b * CD);        // gx -> xs[b]
        attn(bufY, ME, xcat + (size_t)(3 + b) * CD);  // gy -> ys[b]
    }

    k_head<<<1, 256, 0, stream>>>(xcat, g_bn2, b_bn2, Wf, bf, (float*)d_out);
}

// Round 3
// 4898.240 us; speedup vs baseline: 1.3321x; 1.3321x over previous
//
#include <hip/hip_runtime.h>
#include <math.h>

#define NV 20000
#define ME 5000
#define EI_N 160000
#define CD 1024
#define HD 512
#define NCO 10

typedef __attribute__((ext_vector_type(8))) short bf16x8;
typedef __attribute__((ext_vector_type(4))) float f32x4;

// ---------------- reduction helpers ----------------
__device__ __forceinline__ float blockReduceSum(float v) {
    __shared__ float sh[16];
    int lane = threadIdx.x & 63, wid = threadIdx.x >> 6;
    for (int o = 32; o; o >>= 1) v += __shfl_xor(v, o);
    if (lane == 0) sh[wid] = v;
    __syncthreads();
    float r = (threadIdx.x < (blockDim.x >> 6)) ? sh[threadIdx.x] : 0.f;
    if (wid == 0) {
        for (int o = 32; o; o >>= 1) r += __shfl_xor(r, o);
        if (lane == 0) sh[0] = r;
    }
    __syncthreads();
    r = sh[0];
    __syncthreads();
    return r;
}

__device__ __forceinline__ float blockReduceMax(float v) {
    __shared__ float sh[16];
    int lane = threadIdx.x & 63, wid = threadIdx.x >> 6;
    for (int o = 32; o; o >>= 1) v = fmaxf(v, __shfl_xor(v, o));
    if (lane == 0) sh[wid] = v;
    __syncthreads();
    float r = (threadIdx.x < (blockDim.x >> 6)) ? sh[threadIdx.x] : -INFINITY;
    if (wid == 0) {
        for (int o = 32; o; o >>= 1) r = fmaxf(r, __shfl_xor(r, o));
        if (lane == 0) sh[0] = r;
    }
    __syncthreads();
    r = sh[0];
    __syncthreads();
    return r;
}

// ---------------- CSR build ----------------
__global__ void k_count(const int* __restrict__ idx, int* __restrict__ cnt, int n) {
    int i = blockIdx.x * blockDim.x + threadIdx.x;
    if (i < n) atomicAdd(&cnt[idx[i]], 1);
}

__global__ void k_scan(const int* __restrict__ cnt, int* __restrict__ off,
                       int* __restrict__ pos, int n) {
    __shared__ int sdata[1024];
    __shared__ int carry;
    int tid = threadIdx.x;
    if (tid == 0) carry = 0;
    __syncthreads();
    for (int base = 0; base < n; base += 1024) {
        int i = base + tid;
        int v = (i < n) ? cnt[i] : 0;
        sdata[tid] = v;
        __syncthreads();
        for (int o = 1; o < 1024; o <<= 1) {
            int t = (tid >= o) ? sdata[tid - o] : 0;
            __syncthreads();
            sdata[tid] += t;
            __syncthreads();
        }
        int incl = sdata[tid];
        if (i < n) { off[i] = carry + incl - v; pos[i] = 0; }
        __syncthreads();
        if (tid == 1023) carry += incl;
        __syncthreads();
    }
    if (tid == 0) off[n] = carry;
}

__global__ void k_scatter(const int* __restrict__ idx, const int* __restrict__ other,
                          int* __restrict__ pos, const int* __restrict__ off,
                          int* __restrict__ list, int n, int mode) {
    int k = blockIdx.x * blockDim.x + threadIdx.x;
    if (k >= n) return;
    int s = idx[k];
    int p = atomicAdd(&pos[s], 1);
    list[off[s] + p] = mode ? k : other[k];
}

// ---------------- bf16 MFMA GEMM: C = A @ B^T + bias ----------------
// A[M,K] fp32 row-major, B[N,K] fp32 row-major (weights), C[M,N] fp32.
// 128x128 tile, BK=32, 4 waves each own a 64x64 sub-tile (4x4 16x16 frags).
#define BM 128
#define BN 128
#define BK 32
#define LDT 40   // padded LDS stride in shorts (80B: 16B-aligned rows, 2-way-free frag reads)

__device__ __forceinline__ unsigned pk2(float a, float b) {
    union { float f; unsigned u; } x, y; x.f = a; y.f = b;
    unsigned ra = x.u + 0x7fff + ((x.u >> 16) & 1);
    unsigned rb = y.u + 0x7fff + ((y.u >> 16) & 1);
    return (ra >> 16) | (rb & 0xffff0000u);
}
__device__ __forceinline__ uint4 pack8(float4 a, float4 b) {
    uint4 p;
    p.x = pk2(a.x, a.y); p.y = pk2(a.z, a.w);
    p.z = pk2(b.x, b.y); p.w = pk2(b.z, b.w);
    return p;
}

__global__ __launch_bounds__(256) void k_gemm_bf16(const float* __restrict__ A,
                                                   const float* __restrict__ B,
                                                   const float* __restrict__ bias,
                                                   float* __restrict__ C,
                                                   int Mr, int Nc, int K) {
    __shared__ short As[BM][LDT];
    __shared__ short Bs[BN][LDT];
    const int tid = threadIdx.x;
    const int r = tid & 127, half = tid >> 7;
    const int kq = half * 16;                 // K offset this thread stages (16 floats)
    const int rowBase = blockIdx.x * BM, colBase = blockIdx.y * BN;
    const int lane = tid & 63, wid = tid >> 6;
    const int wm = (wid >> 1) * 64, wn = (wid & 1) * 64;
    const int fr = lane & 15, fk = (lane >> 4) * 8;

    f32x4 acc[4][4] = {};
    const int ar = rowBase + r;
    const bool aval = (ar < Mr);
    const float* Ap = A + (size_t)ar * K + kq;
    const float* Bp = B + (size_t)(colBase + r) * K + kq;   // Nc covered by grid exactly

    for (int kk = 0; kk < K; kk += BK) {
        float4 a0, a1, a2, a3;
        if (aval) {
            a0 = *(const float4*)(Ap + 0); a1 = *(const float4*)(Ap + 4);
            a2 = *(const float4*)(Ap + 8); a3 = *(const float4*)(Ap + 12);
        } else {
            a0 = a1 = a2 = a3 = make_float4(0.f, 0.f, 0.f, 0.f);
        }
        float4 b0 = *(const float4*)(Bp + 0), b1 = *(const float4*)(Bp + 4);
        float4 b2 = *(const float4*)(Bp + 8), b3 = *(const float4*)(Bp + 12);
        __syncthreads();   // previous tile's reads done before overwrite
        *(uint4*)&As[r][kq] = pack8(a0, a1);
        *(uint4*)&As[r][kq + 8] = pack8(a2, a3);
        *(uint4*)&Bs[r][kq] = pack8(b0, b1);
        *(uint4*)&Bs[r][kq + 8] = pack8(b2, b3);
        __syncthreads();

        bf16x8 avf[4], bvf[4];
#pragma unroll
        for (int mi = 0; mi < 4; ++mi)
            avf[mi] = *(const bf16x8*)&As[wm + mi * 16 + fr][fk];
#pragma unroll
        for (int ni = 0; ni < 4; ++ni)
            bvf[ni] = *(const bf16x8*)&Bs[wn + ni * 16 + fr][fk];
#pragma unroll
        for (int mi = 0; mi < 4; ++mi)
#pragma unroll
            for (int ni = 0; ni < 4; ++ni)
                acc[mi][ni] = __builtin_amdgcn_mfma_f32_16x16x32_bf16(
                    avf[mi], bvf[ni], acc[mi][ni], 0, 0, 0);
        Ap += BK; Bp += BK;
    }

    // epilogue: row = (lane>>4)*4 + j, col = lane&15 within each 16x16 frag
#pragma unroll
    for (int mi = 0; mi < 4; ++mi) {
        int row0 = rowBase + wm + mi * 16 + (lane >> 4) * 4;
#pragma unroll
        for (int ni = 0; ni < 4; ++ni) {
            int col = colBase + wn + ni * 16 + fr;
            float bv = bias[col];
#pragma unroll
            for (int j = 0; j < 4; ++j) {
                int rr = row0 + j;
                if (rr < Mr) C[(size_t)rr * Nc + col] = acc[mi][ni][j] + bv;
            }
        }
    }
}

// gate: T1 = tanh(T1) * sigmoid(T2)
__global__ void k_gate(float* __restrict__ T1, const float* __restrict__ T2, int n) {
    for (int i = blockIdx.x * blockDim.x + threadIdx.x; i < n; i += gridDim.x * blockDim.x) {
        float t = tanhf(T1[i]);
        float s = 1.f / (1.f + expf(-T2[i]));
        T1[i] = t * s;
    }
}

// ---------------- segment ops ----------------
__global__ void k_v2e(const float* __restrict__ Xin, float* __restrict__ Y,
                      const int* __restrict__ e_off, const int* __restrict__ e_list, int D) {
    int e = blockIdx.x;
    int c = blockIdx.y * blockDim.x + threadIdx.x;
    int beg = e_off[e], end = e_off[e + 1];
    float acc = 0.f;
    for (int p = beg; p < end; ++p) {
        int v = e_list[p];
        acc += Xin[(size_t)v * D + c];
    }
    float deg = (float)(end - beg);
    Y[(size_t)e * D + c] = acc / fmaxf(deg, 1.f);
}

__global__ void k_alpha(const float* __restrict__ Y, const float* __restrict__ we,
                        float* __restrict__ alpha, int Mrows, int D) {
    int w = (blockIdx.x * blockDim.x + threadIdx.x) >> 6;
    int lane = threadIdx.x & 63;
    if (w >= Mrows) return;
    float acc = 0.f;
    for (int c = lane; c < D; c += 64) acc += Y[(size_t)w * D + c] * we[c];
    for (int o = 32; o; o >>= 1) acc += __shfl_xor(acc, o);
    if (!lane) alpha[w] = acc;
}

__global__ void k_segsoftmax(const float* __restrict__ alpha, const int* __restrict__ e_idx,
                             const int* __restrict__ v_off, const int* __restrict__ v_list,
                             float* __restrict__ w, int n) {
    int v = (blockIdx.x * blockDim.x + threadIdx.x) >> 6;
    int lane = threadIdx.x & 63;
    if (v >= n) return;
    int beg = v_off[v], end = v_off[v + 1];
    if (beg == end) return;
    float m = -INFINITY;
    for (int p = beg + lane; p < end; p += 64) {
        float a = alpha[e_idx[v_list[p]]];
        float s = a > 0.f ? a : 0.2f * a;
        m = fmaxf(m, s);
    }
    for (int o = 32; o; o >>= 1) m = fmaxf(m, __shfl_xor(m, o));
    float sum = 0.f;
    for (int p = beg + lane; p < end; p += 64) {
        float a = alpha[e_idx[v_list[p]]];
        float s = a > 0.f ? a : 0.2f * a;
        sum += expf(s - m);
    }
    for (int o = 32; o; o >>= 1) sum += __shfl_xor(sum, o);
    float inv = 1.f / (sum + 1e-12f);
    for (int p = beg + lane; p < end; p += 64) {
        int k = v_list[p];
        float a = alpha[e_idx[k]];
        float s = a > 0.f ? a : 0.2f * a;
        w[k] = expf(s - m) * inv;
    }
}

__global__ void k_e2v(const float* __restrict__ Y, const float* __restrict__ w,
                      const int* __restrict__ e_idx, const int* __restrict__ v_off,
                      const int* __restrict__ v_list, float* __restrict__ Xo, int D, int act) {
    int v = blockIdx.x;
    int c = blockIdx.y * blockDim.x + threadIdx.x;
    int beg = v_off[v], end = v_off[v + 1];
    float acc = 0.f;
    for (int p = beg; p < end; ++p) {
        int k = v_list[p];
        acc += w[k] * Y[(size_t)e_idx[k] * D + c];
    }
    if (act && acc < 0.f) acc = expm1f(acc);
    Xo[(size_t)v * D + c] = acc;
}

// ---------------- attention tail ----------------
__global__ void k_logits(const float* __restrict__ Amat, const float* __restrict__ Wc,
                         const float* __restrict__ bc, float* __restrict__ logits, int n) {
    int i = (blockIdx.x * blockDim.x + threadIdx.x) >> 6;
    int lane = threadIdx.x & 63;
    if (i >= n) return;
    float4 a = *(const float4*)(Amat + (size_t)i * 256 + lane * 4);
    float4 wv = *(const float4*)(Wc + lane * 4);
    float acc = a.x * wv.x + a.y * wv.y + a.z * wv.z + a.w * wv.w;
    for (int o = 32; o; o >>= 1) acc += __shfl_xor(acc, o);
    if (!lane) logits[i] = acc + bc[0];
}

__global__ void k_maxpart(const float* __restrict__ x, int n, float* __restrict__ part) {
    float m = -INFINITY;
    for (int i = blockIdx.x * blockDim.x + threadIdx.x; i < n; i += gridDim.x * blockDim.x)
        m = fmaxf(m, x[i]);
    m = blockReduceMax(m);
    if (!threadIdx.x) part[blockIdx.x] = m;
}
__global__ void k_maxfin(const float* __restrict__ part, int np, float* __restrict__ red) {
    float m = (threadIdx.x < np) ? part[threadIdx.x] : -INFINITY;
    m = blockReduceMax(m);
    if (!threadIdx.x) red[0] = m;
}
__global__ void k_exppart(const float* __restrict__ x, int n, const float* __restrict__ red,
                          float* __restrict__ evec, float* __restrict__ part) {
    float m = red[0];
    float s = 0.f;
    for (int i = blockIdx.x * blockDim.x + threadIdx.x; i < n; i += gridDim.x * blockDim.x) {
        float e = expf(x[i] - m);
        evec[i] = e;
        s += e;
    }
    s = blockReduceSum(s);
    if (!threadIdx.x) part[blockIdx.x] = s;
}
__global__ void k_sumfin(const float* __restrict__ part, int np, float* __restrict__ red) {
    float s = (threadIdx.x < np) ? part[threadIdx.x] : 0.f;
    s = blockReduceSum(s);
    if (!threadIdx.x) red[1] = s;
}

__global__ void k_wcolsum(const float* __restrict__ H, const float* __restrict__ evec,
                          float* __restrict__ gpart, int n, int D, int rows_per) {
    int c = blockIdx.x * blockDim.x + threadIdx.x;
    int r0 = blockIdx.y * rows_per;
    int r1 = min(r0 + rows_per, n);
    float acc = 0.f;
    for (int i = r0; i < r1; ++i) acc += evec[i] * H[(size_t)i * D + c];
    gpart[(size_t)blockIdx.y * D + c] = acc;
}
__global__ void k_colfin(const float* __restrict__ gpart, int nch, int D,
                         const float* __restrict__ red, float* __restrict__ g) {
    int c = blockIdx.x * blockDim.x + threadIdx.x;
    float acc = 0.f;
    for (int ch = 0; ch < nch; ++ch) acc += gpart[(size_t)ch * D + c];
    g[c] = acc / red[1];
}

__global__ void k_matvec(const float* __restrict__ g, const float* __restrict__ W,
                         const float* __restrict__ b, float* __restrict__ out, int D) {
    int j = (blockIdx.x * blockDim.x + threadIdx.x) >> 6;
    int lane = threadIdx.x & 63;
    if (j >= D) return;
    float acc = 0.f;
    for (int k = lane * 4; k < D; k += 256) {
        float4 w4 = *(const float4*)(W + (size_t)j * D + k);
        float4 g4 = *(const float4*)(g + k);
        acc += w4.x * g4.x + w4.y * g4.y + w4.z * g4.z + w4.w * g4.w;
    }
    for (int o = 32; o; o >>= 1) acc += __shfl_xor(acc, o);
    if (!lane) out[j] = acc + b[j];
}

__global__ void k_ln(const float* __restrict__ x, const float* __restrict__ gam,
                     const float* __restrict__ bet, float* __restrict__ out, int D) {
    float s = 0.f, s2 = 0.f;
    for (int i = threadIdx.x; i < D; i += blockDim.x) {
        float v = x[i];
        s += v;
        s2 += v * v;
    }
    s = blockReduceSum(s);
    s2 = blockReduceSum(s2);
    float mu = s / D;
    float var = s2 / D - mu * mu;
    float inv = rsqrtf(var + 1e-5f);
    for (int i = threadIdx.x; i < D; i += blockDim.x)
        out[i] = (x[i] - mu) * inv * gam[i] + bet[i];
}

__global__ void k_head(const float* __restrict__ xcat, const float* __restrict__ g2,
                       const float* __restrict__ b2, const float* __restrict__ Wf,
                       const float* __restrict__ bf, float* __restrict__ out) {
    __shared__ float xn[6 * CD];
    float s = 0.f, s2 = 0.f;
    for (int i = threadIdx.x; i < 6 * CD; i += blockDim.x) {
        float v = xcat[i];
        s += v;
        s2 += v * v;
    }
    s = blockReduceSum(s);
    s2 = blockReduceSum(s2);
    float mu = s / (6 * CD);
    float var = s2 / (6 * CD) - mu * mu;
    float inv = rsqrtf(var + 1e-5f);
    for (int i = threadIdx.x; i < 6 * CD; i += blockDim.x)
        xn[i] = (xcat[i] - mu) * inv * g2[i] + b2[i];
    __syncthreads();
    for (int o = 0; o < NCO; ++o) {
        float a = 0.f;
        for (int i = threadIdx.x; i < 6 * CD; i += blockDim.x)
            a += xn[i] * Wf[(size_t)o * 6 * CD + i];
        a = blockReduceSum(a);
        if (!threadIdx.x) out[o] = a + bf[o];
    }
}

// ---------------- host launcher ----------------
extern "C" void kernel_launch(void* const* d_in, const int* in_sizes, int n_in,
                              void* d_out, int out_size, void* d_ws, size_t ws_size,
                              hipStream_t stream) {
    (void)in_sizes; (void)n_in; (void)out_size; (void)ws_size;

    const float* X[3];
    const int* VI[3];
    const int* EIx[3];
    for (int b = 0; b < 3; ++b) {
        X[b] = (const float*)d_in[3 * b + 0];
        VI[b] = (const int*)d_in[3 * b + 1];
        EIx[b] = (const int*)d_in[3 * b + 2];
    }
    const float* Wt0 = (const float*)d_in[9];
    const float* bt0 = (const float*)d_in[10];
    const float* we0 = (const float*)d_in[11];
    const float* Wt1 = (const float*)d_in[12];
    const float* bt1 = (const float*)d_in[13];
    const float* we1 = (const float*)d_in[14];
    const float* Wa = (const float*)d_in[15];
    const float* ba = (const float*)d_in[16];
    const float* Wb = (const float*)d_in[17];
    const float* bb = (const float*)d_in[18];
    const float* Wc = (const float*)d_in[19];
    const float* bc = (const float*)d_in[20];
    const float* Wout = (const float*)d_in[21];
    const float* bout = (const float*)d_in[22];
    const float* g_bn = (const float*)d_in[23];
    const float* b_bn = (const float*)d_in[24];
    const float* g_bn2 = (const float*)d_in[25];
    const float* b_bn2 = (const float*)d_in[26];
    const float* Wf = (const float*)d_in[27];
    const float* bf = (const float*)d_in[28];

    float* wsf = (float*)d_ws;
    size_t off = 0;
    auto falloc = [&](size_t nelem) {
        float* p = wsf + off;
        off += (nelem + 63) & ~(size_t)63;
        return p;
    };
    float* bufA = falloc((size_t)NV * CD);   // layer-1 out (h)
    float* bufH = falloc((size_t)NV * HD);   // layer-0 out; reused as attn T1/T2
    float* bufY = falloc((size_t)ME * CD);   // Y0/Y1/y
    float* alpha = falloc(ME);
    float* wgt = falloc(EI_N);
    float* logits = falloc(NV);
    float* evec = falloc(NV);
    float* red = falloc(64);
    float* part = falloc(512);
    float* gpart = falloc((size_t)64 * CD);
    float* gvec = falloc(CD);
    float* gout = falloc(CD);
    float* xcat = falloc(8 * 1024);

    int* wsi = (int*)(wsf + off);
    size_t ioff = 0;
    auto ialloc = [&](size_t nelem) {
        int* p = wsi + ioff;
        ioff += (nelem + 63) & ~(size_t)63;
        return p;
    };
    int* e_cnt = ialloc(ME);
    int* e_off = ialloc(ME + 1);
    int* e_pos = ialloc(ME);
    int* e_list = ialloc(EI_N);
    int* v_cnt = ialloc(NV);
    int* v_off = ialloc(NV + 1);
    int* v_pos = ialloc(NV);
    int* v_list = ialloc(EI_N);

    auto attn = [&](const float* Xm, int n, float* dst) {
        float* T1 = bufH;                          // [n,256]
        float* T2 = bufH + (size_t)NV * 256;       // [n,256]
        k_gemm_bf16<<<dim3((n + BM - 1) / BM, 2), 256, 0, stream>>>(Xm, Wa, ba, T1, n, 256, CD);
        k_gemm_bf16<<<dim3((n + BM - 1) / BM, 2), 256, 0, stream>>>(Xm, Wb, bb, T2, n, 256, CD);
        k_gate<<<1024, 256, 0, stream>>>(T1, T2, n * 256);
        k_logits<<<(n + 3) / 4, 256, 0, stream>>>(T1, Wc, bc, logits, n);
        k_maxpart<<<256, 256, 0, stream>>>(logits, n, part);
        k_maxfin<<<1, 256, 0, stream>>>(part, 256, red);
        k_exppart<<<256, 256, 0, stream>>>(logits, n, red, evec, part);
        k_sumfin<<<1, 256, 0, stream>>>(part, 256, red);
        int nch = (n >= NV) ? 50 : 10;
        int rows_per = (n + nch - 1) / nch;
        k_wcolsum<<<dim3(CD / 256, nch), 256, 0, stream>>>(Xm, evec, gpart, n, CD, rows_per);
        k_colfin<<<CD / 256, 256, 0, stream>>>(gpart, nch, CD, red, gvec);
        k_matvec<<<CD / 4, 256, 0, stream>>>(gvec, Wout, bout, gout, CD);
        k_ln<<<1, 256, 0, stream>>>(gout, g_bn, b_bn, dst, CD);
    };

    for (int b = 0; b < 3; ++b) {
        // ---- CSR build ----
        hipMemsetAsync(e_cnt, 0, ME * sizeof(int), stream);
        hipMemsetAsync(v_cnt, 0, NV * sizeof(int), stream);
        k_count<<<(EI_N + 255) / 256, 256, 0, stream>>>(EIx[b], e_cnt, EI_N);
        k_count<<<(EI_N + 255) / 256, 256, 0, stream>>>(VI[b], v_cnt, EI_N);
        k_scan<<<1, 1024, 0, stream>>>(e_cnt, e_off, e_pos, ME);
        k_scan<<<1, 1024, 0, stream>>>(v_cnt, v_off, v_pos, NV);
        k_scatter<<<(EI_N + 255) / 256, 256, 0, stream>>>(EIx[b], VI[b], e_pos, e_off, e_list, EI_N, 0);
        k_scatter<<<(EI_N + 255) / 256, 256, 0, stream>>>(VI[b], EIx[b], v_pos, v_off, v_list, EI_N, 1);

        // ---- UniGAT layer 0 (out=HD, elu) ----
        k_gemm_bf16<<<dim3((NV + BM - 1) / BM, HD / BN), 256, 0, stream>>>(X[b], Wt0, bt0, bufH, NV, HD, CD);
        k_v2e<<<dim3(ME, HD / 256), 256, 0, stream>>>(bufH, bufY, e_off, e_list, HD);
        k_alpha<<<(ME + 3) / 4, 256, 0, stream>>>(bufY, we0, alpha, ME, HD);
        k_segsoftmax<<<(NV + 3) / 4, 256, 0, stream>>>(alpha, EIx[b], v_off, v_list, wgt, NV);
        k_e2v<<<dim3(NV, HD / 256), 256, 0, stream>>>(bufY, wgt, EIx[b], v_off, v_list, bufH, HD, 1);

        // ---- UniGAT layer 1 (out=CD, no act) ----
        k_gemm_bf16<<<dim3((NV + BM - 1) / BM, CD / BN), 256, 0, stream>>>(bufH, Wt1, bt1, bufA, NV, CD, HD);
        k_v2e<<<dim3(ME, CD / 256), 256, 0, stream>>>(bufA, bufY, e_off, e_list, CD);
        k_alpha<<<(ME + 3) / 4, 256, 0, stream>>>(bufY, we1, alpha, ME, CD);
        k_segsoftmax<<<(NV + 3) / 4, 256, 0, stream>>>(alpha, EIx[b], v_off, v_list, wgt, NV);
        k_e2v<<<dim3(NV, CD / 256), 256, 0, stream>>>(bufY, wgt, EIx[b], v_off, v_list, bufA, CD, 0);

        // ---- y = v2e_mean(h) ----
        k_v2e<<<dim3(ME, CD / 256), 256, 0, stream>>>(bufA, bufY, e_off, e_list, CD);

        // ---- gated attention heads ----
        attn(bufA, NV, xcat + (size_t)b * CD);        // gx -> xs[b]
        attn(bufY, ME, xcat + (size_t)(3 + b) * CD);  // gy -> ys[b]
    }

    k_head<<<1, 256, 0, stream>>>(xcat, g_bn2, b_bn2, Wf, bf, (float*)d_out);
}